// Round 6
// baseline (310.067 us; speedup 1.0000x reference)
//
#include <hip/hip_runtime.h>
#include <math.h>

#define GCOUNT 512
#define HDIM 128
#define EPG 2048                 // edge slots per graph (fixed across layers)
#define E_TOTAL (GCOUNT * EPG)   // 1,048,576

typedef __attribute__((ext_vector_type(8))) short short8;
typedef __attribute__((ext_vector_type(4))) float f32x4;

__device__ inline unsigned short f2bf(float f) {
  unsigned int u = __float_as_uint(f);
  return (unsigned short)((u + 0x7FFFu + ((u >> 16) & 1u)) >> 16);
}
__device__ inline float bf2f(unsigned short s) {
  return __uint_as_float(((unsigned int)s) << 16);
}

// ---------------------------------------------------------------- W prepack: bf16 3-split, MFMA-B-fragment layout
// out: ushort Ws[s][kc][ct][lane][j]  (3 x 4 x 8 x 64 x 8 = 96 KB)
__global__ __launch_bounds__(256) void k_wsplit(const float* __restrict__ W,
                                                unsigned short* __restrict__ out) {
  int t = blockIdx.x * 256 + threadIdx.x;   // 2048 = (kc*8+ct)*64+lane
  int lane = t & 63;
  int ct = (t >> 6) & 7;
  int kc = t >> 9;
  int kbase = kc * 32 + (lane >> 4) * 8;
  int col = ct * 16 + (lane & 15);
#pragma unroll
  for (int j = 0; j < 8; j++) {
    float w = W[(size_t)(kbase + j) * HDIM + col];
    unsigned short h0 = f2bf(w);  float g0 = bf2f(h0);
    float r1 = w - g0;
    unsigned short h1 = f2bf(r1); float g1 = bf2f(h1);
    unsigned short h2 = f2bf(r1 - g1);
    int base = (kc * 8 + ct) * 512 + lane * 8 + j;
    out[base]         = h0;
    out[base + 16384] = h1;
    out[base + 32768] = h2;
  }
}

// ---------------------------------------------------------------- fused layer, wave-specialized
__global__ __launch_bounds__(1024, 1) void k_layer(
    const float* __restrict__ xIn, const int* __restrict__ ei0,
    const unsigned int* __restrict__ eIn, unsigned int* __restrict__ eOut,
    float* poolOut, const unsigned short* __restrict__ Ws,
    const float* __restrict__ bias, const float* __restrict__ p,
    const float* __restrict__ Wg, const float* __restrict__ bgp,
    float* outp, int n, int k, int first, int accflag) {

  __shared__ __align__(16) float h_s[256 * 132];   // 135168 B
  __shared__ __align__(16) float2 ep2[EPG];        // 16384 B (dinv, byteoff) pairs; reused as pp
  __shared__ int cnt[256];                         // degree -> nmap
  __shared__ int ofs[256];
  __shared__ int rp[260];
  __shared__ float sc[256];                        // sort exchange -> att weights
  __shared__ int idx[256];
  __shared__ float tn[256];
  __shared__ float hd[256];                        // h . Wg per row
  __shared__ float dinv_s[256];
  __shared__ float rawsc_s[256];
  __shared__ float red[8];
  __shared__ float snorm_s;

  int g = blockIdx.x, t = threadIdx.x;
  int lane = t & 63, wv = t >> 6;
  int eb = g * EPG;

  // ================= I1: gemm (waves < T2) || edge load + cnt zero (waves >= 8)
  int T2 = (n + 31) >> 5;
  int esl[4], edl[4];
  if (wv < T2) {
    int rbase = wv * 32;
    // self-stage my 32 rows (coalesced)
    const float4* xg4 = (const float4*)(xIn + ((size_t)g * n + rbase) * HDIM);
    for (int i = lane; i < 1024; i += 64) {
      int r = i >> 5, q = i & 31;
      *(float4*)&h_s[(rbase + r) * 132 + (q << 2)] = xg4[i];
    }
    int arow = lane & 15, kgrp = (lane >> 4) * 8;
    f32x4 acc[2][8];
#pragma unroll
    for (int rt = 0; rt < 2; rt++)
#pragma unroll
      for (int ct = 0; ct < 8; ct++) acc[rt][ct] = (f32x4){0.f, 0.f, 0.f, 0.f};
#pragma unroll
    for (int kc = 0; kc < 4; kc++) {
      short8 fa0[2], fa1[2], fa2[2];
#pragma unroll
      for (int rt = 0; rt < 2; rt++) {
        const float* ap = &h_s[(rbase + rt * 16 + arow) * 132 + kc * 32 + kgrp];
        float4 x0 = *(const float4*)ap;
        float4 x1 = *(const float4*)(ap + 4);
        float v[8] = {x0.x, x0.y, x0.z, x0.w, x1.x, x1.y, x1.z, x1.w};
#pragma unroll
        for (int j = 0; j < 8; j++) {
          float a = v[j];
          unsigned short h0 = f2bf(a);  float g0 = bf2f(h0);
          float r1 = a - g0;
          unsigned short h1 = f2bf(r1); float g1 = bf2f(h1);
          unsigned short h2 = f2bf(r1 - g1);
          fa0[rt][j] = (short)h0; fa1[rt][j] = (short)h1; fa2[rt][j] = (short)h2;
        }
      }
#pragma unroll
      for (int ct = 0; ct < 8; ct++) {
        const unsigned short* wb = Ws + (kc * 8 + ct) * 512 + lane * 8;
        short8 b0 = *(const short8*)wb;
        short8 b1 = *(const short8*)(wb + 16384);
        short8 b2 = *(const short8*)(wb + 32768);
#pragma unroll
        for (int rt = 0; rt < 2; rt++) {
          acc[rt][ct] = __builtin_amdgcn_mfma_f32_16x16x32_bf16(fa0[rt], b0, acc[rt][ct], 0, 0, 0);
          acc[rt][ct] = __builtin_amdgcn_mfma_f32_16x16x32_bf16(fa0[rt], b1, acc[rt][ct], 0, 0, 0);
          acc[rt][ct] = __builtin_amdgcn_mfma_f32_16x16x32_bf16(fa1[rt], b0, acc[rt][ct], 0, 0, 0);
          acc[rt][ct] = __builtin_amdgcn_mfma_f32_16x16x32_bf16(fa1[rt], b1, acc[rt][ct], 0, 0, 0);
          acc[rt][ct] = __builtin_amdgcn_mfma_f32_16x16x32_bf16(fa0[rt], b2, acc[rt][ct], 0, 0, 0);
          acc[rt][ct] = __builtin_amdgcn_mfma_f32_16x16x32_bf16(fa2[rt], b0, acc[rt][ct], 0, 0, 0);
        }
      }
    }
    int crow = (lane >> 4) * 4, ccol = lane & 15;
#pragma unroll
    for (int rt = 0; rt < 2; rt++)
#pragma unroll
      for (int ct = 0; ct < 8; ct++)
#pragma unroll
        for (int reg = 0; reg < 4; reg++)
          h_s[(rbase + rt * 16 + crow + reg) * 132 + ct * 16 + ccol] = acc[rt][ct][reg];
  } else if (wv >= 8) {
    int tt = t - 512;
    if (tt < 256) cnt[tt] = 0;
#pragma unroll
    for (int q = 0; q < 4; q++) {
      int e = tt + q * 512;
      if (first) {
        esl[q] = ei0[eb + e] - g * n;
        edl[q] = ei0[E_TOTAL + eb + e] - g * n;
      } else {
        unsigned int u = eIn[eb + e];
        if (u == 0xFFFFFFFFu) { esl[q] = -1; edl[q] = 0; }
        else { esl[q] = (int)(u & 0xFFFFu); edl[q] = (int)(u >> 16); }
      }
    }
  }
  __syncthreads();                                  // BAR1

  // ================= I2: histogram
  if (wv >= 8) {
#pragma unroll
    for (int q = 0; q < 4; q++)
      if (esl[q] >= 0) atomicAdd(&cnt[edl[q]], 1);
  }
  __syncthreads();                                  // BAR2

  // ================= I3: dinv + scan (wave0) + snorm (wave1)
  if (t < 256) dinv_s[t] = rsqrtf((float)cnt[t] + 1.0f);
  if (wv == 0) {
    int4 c4 = *(const int4*)&cnt[lane << 2];
    int s4 = c4.x + c4.y + c4.z + c4.w;
    int run = s4;
#pragma unroll
    for (int o = 1; o < 64; o <<= 1) {
      int v = __shfl_up(run, o);
      if (lane >= o) run += v;
    }
    int base = run - s4;
    int b1 = base + c4.x, b2 = b1 + c4.y, b3 = b2 + c4.z;
    int li = lane << 2;
    rp[li] = base; rp[li + 1] = b1; rp[li + 2] = b2; rp[li + 3] = b3;
    ofs[li] = base; ofs[li + 1] = b1; ofs[li + 2] = b2; ofs[li + 3] = b3;
    if (lane == 63) rp[256] = run;
  }
  if (wv == 1) {
    float q = p[lane] * p[lane] + p[lane + 64] * p[lane + 64];
#pragma unroll
    for (int o = 32; o > 0; o >>= 1) q += __shfl_xor(q, o);
    if (lane == 0) snorm_s = sqrtf(q);
  }
  __syncthreads();                                  // BAR3

  // ================= I4: scatter pairs || preset nmap
  if (t < 256) cnt[t] = -1;
  if (wv >= 8) {
#pragma unroll
    for (int q = 0; q < 4; q++)
      if (esl[q] >= 0) {
        int pos = atomicAdd(&ofs[edl[q]], 1);
        ep2[pos] = make_float2(dinv_s[esl[q]], __int_as_float(esl[q] * 528));
      }
  }
  __syncthreads();                                  // BAR4

  // ================= I5: aggregate (dual-dst ILP) + score/gate dots
  int c = lane << 1;
  char* hb = (char*)h_s + ((size_t)lane << 3);
  float2 bV = *(const float2*)&bias[c];
  float2 pV = *(const float2*)&p[c];
  float2 wV = *(const float2*)&Wg[c];
  float a0[16], a1[16];
#pragma unroll
  for (int ii = 0; ii < 8; ii++) {
    int d0 = wv + (ii << 4);
    int d1 = d0 + 128;
    bool has1 = (d1 < n);
    int j0 = rp[d0], e0 = rp[d0 + 1];
    int j1 = 0, e1 = 0;
    float dv1 = 0.f;
    if (has1) { j1 = rp[d1]; e1 = rp[d1 + 1]; dv1 = dinv_s[d1]; }
    float dv0 = dinv_s[d0];
    float u00 = 0.f, u01 = 0.f, u10 = 0.f, u11 = 0.f;
    while (j0 + 2 <= e0 && j1 + 2 <= e1) {
      float2 q0 = ep2[j0], q1 = ep2[j0 + 1];
      float2 q2 = ep2[j1], q3 = ep2[j1 + 1];
      float2 v0 = *(const float2*)(hb + __float_as_int(q0.y));
      float2 v1 = *(const float2*)(hb + __float_as_int(q1.y));
      float2 v2 = *(const float2*)(hb + __float_as_int(q2.y));
      float2 v3 = *(const float2*)(hb + __float_as_int(q3.y));
      u00 = fmaf(q0.x, v0.x, u00); u01 = fmaf(q0.x, v0.y, u01);
      u00 = fmaf(q1.x, v1.x, u00); u01 = fmaf(q1.x, v1.y, u01);
      u10 = fmaf(q2.x, v2.x, u10); u11 = fmaf(q2.x, v2.y, u11);
      u10 = fmaf(q3.x, v3.x, u10); u11 = fmaf(q3.x, v3.y, u11);
      j0 += 2; j1 += 2;
    }
    while (j0 + 2 <= e0) {
      float2 q0 = ep2[j0], q1 = ep2[j0 + 1];
      float2 v0 = *(const float2*)(hb + __float_as_int(q0.y));
      float2 v1 = *(const float2*)(hb + __float_as_int(q1.y));
      u00 = fmaf(q0.x, v0.x, u00); u01 = fmaf(q0.x, v0.y, u01);
      u00 = fmaf(q1.x, v1.x, u00); u01 = fmaf(q1.x, v1.y, u01);
      j0 += 2;
    }
    while (j0 < e0) {
      float2 q0 = ep2[j0];
      float2 v0 = *(const float2*)(hb + __float_as_int(q0.y));
      u00 = fmaf(q0.x, v0.x, u00); u01 = fmaf(q0.x, v0.y, u01);
      j0++;
    }
    while (j1 + 2 <= e1) {
      float2 q2 = ep2[j1], q3 = ep2[j1 + 1];
      float2 v2 = *(const float2*)(hb + __float_as_int(q2.y));
      float2 v3 = *(const float2*)(hb + __float_as_int(q3.y));
      u10 = fmaf(q2.x, v2.x, u10); u11 = fmaf(q2.x, v2.y, u11);
      u10 = fmaf(q3.x, v3.x, u10); u11 = fmaf(q3.x, v3.y, u11);
      j1 += 2;
    }
    while (j1 < e1) {
      float2 q2 = ep2[j1];
      float2 v2 = *(const float2*)(hb + __float_as_int(q2.y));
      u10 = fmaf(q2.x, v2.x, u10); u11 = fmaf(q2.x, v2.y, u11);
      j1++;
    }
    {
      float2 vs = *(const float2*)(hb + d0 * 528);
      float r0 = fmaxf(fmaf(dv0, fmaf(vs.x, dv0, u00), bV.x), 0.f);
      float r1 = fmaxf(fmaf(dv0, fmaf(vs.y, dv0, u01), bV.y), 0.f);
      a0[ii] = r0; a1[ii] = r1;
      float s1 = fmaf(r0, pV.x, r1 * pV.y);
      float g1 = fmaf(r0, wV.x, r1 * wV.y);
#pragma unroll
      for (int o = 32; o > 0; o >>= 1) {
        s1 += __shfl_xor(s1, o);
        g1 += __shfl_xor(g1, o);
      }
      if (lane == 0) { rawsc_s[d0] = s1; hd[d0] = g1; }
    }
    if (has1) {
      float2 vs = *(const float2*)(hb + d1 * 528);
      float r0 = fmaxf(fmaf(dv1, fmaf(vs.x, dv1, u10), bV.x), 0.f);
      float r1 = fmaxf(fmaf(dv1, fmaf(vs.y, dv1, u11), bV.y), 0.f);
      a0[ii + 8] = r0; a1[ii + 8] = r1;
      float s1 = fmaf(r0, pV.x, r1 * pV.y);
      float g1 = fmaf(r0, wV.x, r1 * wV.y);
#pragma unroll
      for (int o = 32; o > 0; o >>= 1) {
        s1 += __shfl_xor(s1, o);
        g1 += __shfl_xor(g1, o);
      }
      if (lane == 0) { rawsc_s[d1] = s1; hd[d1] = g1; }
    } else {
      a0[ii + 8] = 0.f; a1[ii + 8] = 0.f;
    }
  }
  __syncthreads();                                  // BAR5

  // ================= I6: write aggregated h back
#pragma unroll
  for (int ii = 0; ii < 16; ii++) {
    int d = wv + (ii << 4);
    if (d < n) *(float2*)(hb + d * 528) = make_float2(a0[ii], a1[ii]);
  }
  __syncthreads();                                  // BAR6

  // ================= I7: bitonic top-k sort in registers (keys = raw dot, desc, idx asc)
  float key = -INFINITY;
  int id = t;
  if (t < n) key = rawsc_s[t];
  for (int size = 2; size <= 256; size <<= 1) {
    for (int stride = size >> 1; stride > 0; stride >>= 1) {
      if (stride > 32) {
        if (t < 256) { sc[t] = key; idx[t] = id; }
        __syncthreads();
        float pk = 0.f; int pi = 0;
        if (t < 256) { pk = sc[t ^ stride]; pi = idx[t ^ stride]; }
        __syncthreads();
        if (t < 256) {
          bool want = ((t & size) == 0);
          bool lowr = ((t & stride) == 0);
          bool mineFirst = (key > pk) || (key == pk && id < pi);
          if (mineFirst != (want == lowr)) { key = pk; id = pi; }
        }
      } else {
        if (t < 256) {
          float pk = __shfl_xor(key, stride);
          int pi = __shfl_xor(id, stride);
          bool want = ((t & size) == 0);
          bool lowr = ((t & stride) == 0);
          bool mineFirst = (key > pk) || (key == pk && id < pi);
          if (mineFirst != (want == lowr)) { key = pk; id = pi; }
        }
      }
    }
  }
  if (t < 256) idx[t] = id;
  __syncthreads();                                  // BAR7

  // ================= S1: tn, nmap, gates + per-wave max
  float gate = -INFINITY;
  float tnv = 0.f;
  if (t < k) {
    tnv = tanhf(key / snorm_s);
    tn[t] = tnv;
    cnt[id] = t;
    gate = fmaf(hd[id], tnv, bgp[0]);
  }
  if (wv < 4) {
    float m = gate;
#pragma unroll
    for (int o = 32; o > 0; o >>= 1) m = fmaxf(m, __shfl_xor(m, o));
    if (lane == 0) red[wv] = m;
  }
  __syncthreads();                                  // BAR8

  // ================= S2: softmax exp+sum (waves 0-3) || pooled write (waves 4-15)
  float ex = 0.f;
  if (wv < 4) {
    float m = fmaxf(fmaxf(red[0], red[1]), fmaxf(red[2], red[3]));
    ex = (t < k) ? __expf(gate - m) : 0.f;
    float s = ex;
#pragma unroll
    for (int o = 32; o > 0; o >>= 1) s += __shfl_xor(s, o);
    if (lane == 0) red[4 + wv] = s;
  } else if (poolOut) {
    float4* pg = (float4*)(poolOut + (size_t)g * k * HDIM);
    for (int i = t - 256; i < k * 32; i += 768) {
      int r = i >> 5, q = i & 31;
      float4 v = *(const float4*)&h_s[idx[r] * 132 + (q << 2)];
      float tr = tn[r];
      v.x *= tr; v.y *= tr; v.z *= tr; v.w *= tr;
      pg[i] = v;
    }
  }
  __syncthreads();                                  // BAR9

  // ================= S3: att weights (t<256) || edge remap (waves 8-15)
  if (t < 256) {
    float inv = 1.f / (red[4] + red[5] + red[6] + red[7]);
    sc[t] = (t < k) ? ex * inv * tn[t] : 0.f;
  } else if (wv >= 8 && eOut) {
    int tt = t - 512;
#pragma unroll
    for (int q = 0; q < 4; q++) {
      int e = tt + q * 512;
      int s_, d_;
      bool vld;
      if (first) {
        s_ = ei0[eb + e] - g * n;
        d_ = ei0[E_TOTAL + eb + e] - g * n;
        vld = true;
      } else {
        unsigned int u = eIn[eb + e];
        vld = (u != 0xFFFFFFFFu);
        s_ = (int)(u & 0xFFFFu); d_ = (int)(u >> 16);
      }
      unsigned int o = 0xFFFFFFFFu;
      if (vld) {
        int ns = cnt[s_], nd = cnt[d_];
        if (ns >= 0 && nd >= 0) o = (unsigned)ns | ((unsigned)nd << 16);
      }
      eOut[eb + e] = o;
    }
  }
  __syncthreads();                                  // BAR10

  // ================= S4+S5: attention-weighted sum (4-way parallel over k)
  if (t < 512) {
    int grp = t >> 7, c2 = t & 127;
    float part = 0.f;
    for (int r = grp; r < k; r += 4)
      part = fmaf(sc[r], h_s[idx[r] * 132 + c2], part);
    ((float*)ep2)[grp * 128 + c2] = part;
  }
  __syncthreads();                                  // BAR11
  if (t < 128) {
    const float* pp = (const float*)ep2;
    float o = pp[t] + pp[128 + t] + pp[256 + t] + pp[384 + t];
    size_t oo = (size_t)g * HDIM + t;
    outp[oo] = accflag ? (outp[oo] + o) : o;
  }
}

// ================================================================ launch
extern "C" void kernel_launch(void* const* d_in, const int* in_sizes, int n_in,
                              void* d_out, int out_size, void* d_ws, size_t ws_size,
                              hipStream_t stream) {
  const float* x  = (const float*)d_in[0];
  const int*   ei = (const int*)d_in[1];
  const float* W0 = (const float*)d_in[2];
  const float* b0 = (const float*)d_in[3];
  const float* p0 = (const float*)d_in[4];
  const float* W1 = (const float*)d_in[5];
  const float* b1 = (const float*)d_in[6];
  const float* p1 = (const float*)d_in[7];
  const float* W2 = (const float*)d_in[8];
  const float* b2 = (const float*)d_in[9];
  const float* p2 = (const float*)d_in[10];
  const float* Wg = (const float*)d_in[11];
  const float* bg = (const float*)d_in[12];
  float* out = (float*)d_out;

  unsigned char* ws = (unsigned char*)d_ws;
  float* buf0 = (float*)(ws);                              // 64 MB (pooled L0)
  float* buf1 = (float*)(ws + 67108864ull);                // 64 MB (pooled L1)
  unsigned int* eb0 = (unsigned int*)(ws + 134217728ull);  // 4 MB packed edges
  unsigned int* eb1 = (unsigned int*)(ws + 138412032ull);  // 4 MB
  unsigned short* Wsp = (unsigned short*)(ws + 142606336ull); // 96 KB

  // layer 0: n=256 -> k=205
  k_wsplit<<<8, 256, 0, stream>>>(W0, Wsp);
  k_layer<<<GCOUNT, 1024, 0, stream>>>(x, ei, nullptr, eb0, buf0, Wsp,
                                       b0, p0, Wg, bg, out, 256, 205, 1, 0);
  // layer 1: n=205 -> k=164
  k_wsplit<<<8, 256, 0, stream>>>(W1, Wsp);
  k_layer<<<GCOUNT, 1024, 0, stream>>>(buf0, nullptr, eb0, eb1, buf1, Wsp,
                                       b1, p1, Wg, bg, out, 205, 164, 0, 1);
  // layer 2: n=164 -> k=132 (no pooled output, no edge output)
  k_wsplit<<<8, 256, 0, stream>>>(W2, Wsp);
  k_layer<<<GCOUNT, 1024, 0, stream>>>(buf1, nullptr, eb1, nullptr, nullptr, Wsp,
                                       b2, p2, Wg, bg, out, 164, 132, 0, 1);
}